// Round 5
// baseline (1391.782 us; speedup 1.0000x reference)
//
#include <hip/hip_runtime.h>
#include <cstddef>

typedef unsigned int uint;
typedef unsigned short ushort;

// ---- problem constants (from reference) ----
constexpr int BATCH = 2;
constexpr int SEQ   = 2523;
constexpr int CDIM  = 768;
constexpr int NH    = 12;
constexpr int HD    = 64;
constexpr int NM    = 1682;               // template rows
constexpr int NMEM  = 4096;
constexpr int NFULL = NMEM + SEQ;         // 6619
constexpr int NFT   = 6656;               // vT padded row stride
constexpr int TOPM  = 841;                // int(0.50*1682)
constexpr int TOPS  = 1654;               // int(0.25*6619)
constexpr int IDC   = CDIM + NH;          // 780
constexpr int QT_T  = (NM + 31) / 32;         // 53 template q-tiles per bh
constexpr int QT_S  = (SEQ - NM + 31) / 32;   // 27 search q-tiles per bh
constexpr int ITEMS_PER_BH = QT_T + QT_S;     // 80
constexpr int NBH   = BATCH * NH;             // 24

using bf16x8 = __attribute__((ext_vector_type(8))) short;
using f32x4  = __attribute__((ext_vector_type(4))) float;

__device__ __forceinline__ float bf2f(ushort u){ return __uint_as_float(((uint)u) << 16); }
__device__ __forceinline__ ushort f2bf(float f){
  uint x = __float_as_uint(f);
  x += 0x7fffu + ((x >> 16) & 1u);        // RNE
  return (ushort)(x >> 16);
}
// 16-bit monotone selection key from score (x1024 fixed-point)
__device__ __forceinline__ uint qkey(float s){
  int q16 = __float2int_rn(s * 1024.f);
  q16 = q16 > 32767 ? 32767 : (q16 < -32768 ? -32768 : q16);
  return ((uint)(ushort)(short)q16) ^ 0x8000u;
}

// ======================= dtype detector =======================
__global__ void detect_mode(const uint* __restrict__ w, int* __restrict__ mode){
  __shared__ int cnt;
  if (threadIdx.x == 0) cnt = 0;
  __syncthreads();
  uint v = w[threadIdx.x * 97];
  uint e = (v >> 7) & 0xFFu;
  if (e >= 100u && e <= 135u) atomicAdd(&cnt, 1);
  __syncthreads();
  if (threadIdx.x == 0) mode[0] = (cnt > 128) ? 1 : 0;   // 1 = bf16, 0 = fp32
}

// ======================= input conversion =======================
__global__ void conv_in(const void* __restrict__ src, ushort* __restrict__ dst,
                        int n, const int* __restrict__ modep){
  int i = blockIdx.x*256 + threadIdx.x;
  if (i >= n) return;
  if (modep[0]) dst[i] = ((const ushort*)src)[i];
  else          dst[i] = f2bf(((const float*)src)[i]);
}

__global__ void conv_bias(const void* __restrict__ src, float* __restrict__ dst,
                          int n, const int* __restrict__ modep){
  int i = blockIdx.x*256 + threadIdx.x;
  if (i >= n) return;
  dst[i] = modep[0] ? bf2f(((const ushort*)src)[i]) : ((const float*)src)[i];
}

// mem_k -> kfull head (row-major); mem_v -> vT head (transposed, stride NFT)
__global__ void conv_mem(const void* __restrict__ mk, const void* __restrict__ mv,
                         ushort* __restrict__ kf, ushort* __restrict__ vT,
                         const int* __restrict__ modep){
  int idx = blockIdx.x*256 + threadIdx.x;
  constexpr int total = BATCH*NH*NMEM*HD;
  if (idx >= total) return;
  int dd = idx & 63;
  int j  = (idx >> 6) % NMEM;
  int bh = idx / (NMEM*HD);
  ushort k_, v_;
  if (modep[0]){ k_ = ((const ushort*)mk)[idx]; v_ = ((const ushort*)mv)[idx]; }
  else { k_ = f2bf(((const float*)mk)[idx]); v_ = f2bf(((const float*)mv)[idx]); }
  kf[((size_t)bh*NFULL + j)*HD + dd] = k_;
  vT[((size_t)bh*HD + dd)*NFT + j]   = v_;
}

// ======================= GEMM (m97 structure, 128x128 tile) =======================
#define GEMM_PROLOGUE(M_, Nc_, K_) \
  __shared__ ushort As[128][40]; \
  __shared__ ushort Bs[128][40]; \
  const int tid  = threadIdx.x; \
  const int wave = tid >> 6, lane = tid & 63; \
  const int quad = lane >> 4, l16 = lane & 15; \
  const int row0 = blockIdx.x * 128, col0 = blockIdx.y * 128; \
  const int wr = (wave >> 1) * 64, wc = (wave & 1) * 64; \
  f32x4 acc[4][4] = {}; \
  for (int k0 = 0; k0 < (K_); k0 += 32){ \
    __syncthreads(); \
    for (int c = tid; c < 512; c += 256){ \
      int r = c >> 2, ck = c & 3; \
      uint4 v = {0,0,0,0}; \
      int gr = row0 + r; \
      if (gr < (M_)) v = *(const uint4*)(A + (size_t)gr * (K_) + k0 + ck*8); \
      *(uint4*)(&As[r][ck*8]) = v; \
    } \
    for (int c = tid; c < 512; c += 256){ \
      int r = c >> 2, ck = c & 3; \
      uint4 v = {0,0,0,0}; \
      int gc = col0 + r; \
      if (gc < (Nc_)) v = *(const uint4*)(Bw + (size_t)gc * (K_) + k0 + ck*8); \
      *(uint4*)(&Bs[r][ck*8]) = v; \
    } \
    __syncthreads(); \
    bf16x8 af[4], bfr[4]; \
    _Pragma("unroll") \
    for (int i = 0; i < 4; i++) af[i]  = *(const bf16x8*)(&As[wr + 16*i + l16][quad*8]); \
    _Pragma("unroll") \
    for (int j = 0; j < 4; j++) bfr[j] = *(const bf16x8*)(&Bs[wc + 16*j + l16][quad*8]); \
    _Pragma("unroll") \
    for (int i = 0; i < 4; i++) \
      _Pragma("unroll") \
      for (int j = 0; j < 4; j++) \
        acc[i][j] = __builtin_amdgcn_mfma_f32_16x16x32_bf16(af[i], bfr[j], acc[i][j], 0, 0, 0); \
  }
// C/D layout (verified m89/m91): col = lane&15, row = (lane>>4)*4 + reg

__global__ __launch_bounds__(256)
void gemm_idkv(const ushort* __restrict__ A, const ushort* __restrict__ Bw,
               const float* __restrict__ biasf, float* __restrict__ Cf)
{
  constexpr int M = BATCH*NM, Nc = IDC, K = CDIM;
  GEMM_PROLOGUE(M, Nc, K)
  #pragma unroll
  for (int i = 0; i < 4; i++)
    #pragma unroll
    for (int j = 0; j < 4; j++)
      #pragma unroll
      for (int r = 0; r < 4; r++){
        int row = row0 + wr + 16*i + quad*4 + r;
        int col = col0 + wc + 16*j + l16;
        if (row < M && col < Nc)
          Cf[(size_t)row*Nc + col] = acc[i][j][r] + biasf[col];
      }
}

// qkv GEMM + fused epilogue: q->qallb(bf16,scaled), k->kfull tail + kmod + out_km,
// v->vT tail (transposed) + out_vm.
__global__ __launch_bounds__(256)
void gemm_qkv(const ushort* __restrict__ A, const ushort* __restrict__ Bw,
              const float* __restrict__ idkvf, ushort* __restrict__ qallb,
              ushort* __restrict__ kfull, ushort* __restrict__ vT,
              ushort* __restrict__ kmod, void* __restrict__ out_base,
              const int* __restrict__ modep)
{
  constexpr int M = BATCH*SEQ, Nc = 3*CDIM, K = CDIM;
  GEMM_PROLOGUE(M, Nc, K)
  const int mode = modep[0];
  constexpr size_t OKM = (size_t)BATCH*SEQ*CDIM;
  constexpr size_t OVM = OKM + (size_t)BATCH*NH*NM*HD;
  #pragma unroll
  for (int i = 0; i < 4; i++)
    #pragma unroll
    for (int j = 0; j < 4; j++)
      #pragma unroll
      for (int r = 0; r < 4; r++){
        int row = row0 + wr + 16*i + quad*4 + r;
        int col = col0 + wc + 16*j + l16;
        if (row < M && col < Nc){
          float v = acc[i][j][r];
          int b = row / SEQ, n = row - b*SEQ;
          if (col < CDIM){
            int h = col >> 6, dd = col & 63;
            qallb[((size_t)(b*NH+h)*SEQ + n)*HD + dd] = f2bf(v * 0.125f);
          } else if (col < 2*CDIM){
            int c = col - CDIM; int h = c >> 6, dd = c & 63;
            size_t bh = (size_t)b*NH + h;
            kfull[(bh*NFULL + NMEM + n)*HD + dd] = f2bf(v);
            if (n < NM){
              float idk = idkvf[((size_t)b*NM + n)*IDC + h];
              float km = v * (1.f + tanhf(idk));
              size_t o = (bh*NM + n)*HD + dd;
              kmod[o] = f2bf(km);
              if (mode) ((ushort*)out_base)[OKM + o] = f2bf(km);
              else      ((float*) out_base)[OKM + o] = km;
            }
          } else {
            int c = col - 2*CDIM; int h = c >> 6, dd = c & 63;
            size_t bh = (size_t)b*NH + h;
            float vv = v;
            if (n < NM){
              vv = v + idkvf[((size_t)b*NM + n)*IDC + NH + c];
              size_t o = (bh*NM + n)*HD + dd;
              if (mode) ((ushort*)out_base)[OVM + o] = f2bf(vv);
              else      ((float*) out_base)[OVM + o] = vv;
            }
            vT[(bh*HD + dd)*NFT + NMEM + n] = f2bf(vv);
          }
        }
      }
}

__global__ __launch_bounds__(256)
void gemm_proj(const ushort* __restrict__ A, const ushort* __restrict__ Bw,
               const float* __restrict__ biasf, void* __restrict__ out_base,
               const int* __restrict__ modep)
{
  constexpr int M = BATCH*SEQ, Nc = CDIM, K = CDIM;
  GEMM_PROLOGUE(M, Nc, K)
  const int mode = modep[0];
  #pragma unroll
  for (int i = 0; i < 4; i++)
    #pragma unroll
    for (int j = 0; j < 4; j++)
      #pragma unroll
      for (int r = 0; r < 4; r++){
        int row = row0 + wr + 16*i + quad*4 + r;
        int col = col0 + wc + 16*j + l16;
        if (row < M && col < Nc){
          float v = acc[i][j][r] + biasf[col];
          size_t o = (size_t)row*Nc + col;
          if (mode) ((ushort*)out_base)[o] = f2bf(v);
          else      ((float*) out_base)[o] = v;
        }
      }
}

// ======================= slab-free MFMA top-k attention (merged) =======================
// One dispatch covers BOTH attentions. XCD-aware decode: xcd = blk&7; items for
// bh = xcd + 8*group are contiguous per XCD (template tiles then search tiles per
// bh), so the concurrently-live K/V working set per XCD (~1.9 MB) fits its 4 MB L2
// and passes 2/3 re-read K from L2 instead of HBM.
__device__ __forceinline__ void score_tile(
    const bf16x8 afr[2][2], const ushort* __restrict__ Kb, int Kn,
    int j0, int l16, int quad, f32x4 cg[2][2])
{
  #pragma unroll
  for (int g = 0; g < 2; g++){
    int jj = j0 + g*16 + l16;
    int jc = jj < Kn ? jj : Kn-1;
    const ushort* kr = Kb + (size_t)jc*HD;
    bf16x8 b0 = *(const bf16x8*)(kr + quad*8);
    bf16x8 b1 = *(const bf16x8*)(kr + 32 + quad*8);
    f32x4 c0 = {}, c1 = {};
    c0 = __builtin_amdgcn_mfma_f32_16x16x32_bf16(afr[0][0], b0, c0, 0,0,0);
    c0 = __builtin_amdgcn_mfma_f32_16x16x32_bf16(afr[0][1], b1, c0, 0,0,0);
    c1 = __builtin_amdgcn_mfma_f32_16x16x32_bf16(afr[1][0], b0, c1, 0,0,0);
    c1 = __builtin_amdgcn_mfma_f32_16x16x32_bf16(afr[1][1], b1, c1, 0,0,0);
    cg[0][g] = c0; cg[1][g] = c1;
  }
}

__global__ __launch_bounds__(256, 3)
void attn_topk4(const ushort* __restrict__ qallb, const ushort* __restrict__ kmod,
                const ushort* __restrict__ kfull, const ushort* __restrict__ vT,
                ushort* __restrict__ xcat)
{
  __shared__ uint ubuf[10272];          // hist 32x257 | lst 32x64 | (late) redf 2048 f32
  __shared__ ushort Pt[4][32][36];      // per-wave P transpose tile [wave][jl][row]
  __shared__ float zpart[32][4];
  __shared__ uint hi8[32], needs[32], tks[32], cnts[32];
  __shared__ int jcuts[32];
  uint* lst = ubuf + 8224;
  float* redf = (float*)ubuf;

  const int tid = threadIdx.x;
  const int wave = tid >> 6, lane = tid & 63;
  const int quad = lane >> 4, l16 = lane & 15;

  // ---- XCD-aware item decode ----
  const int xcd = blockIdx.x & 7;
  const int i   = blockIdx.x >> 3;          // [0, 240)
  const int grp = i / ITEMS_PER_BH;         // [0, 3)
  const int jj_ = i - grp * ITEMS_PER_BH;   // [0, 80)
  const int bh  = xcd + 8 * grp;
  int qt, qbase, nqtot, Kn, ksel, vjoff;
  const ushort* Kb;
  if (jj_ < QT_T){ qt = jj_;        qbase = 0;  nqtot = NM;      Kn = NM;    ksel = TOPM; vjoff = NMEM;
                   Kb = kmod  + (size_t)bh * NM * HD; }
  else           { qt = jj_ - QT_T; qbase = NM; nqtot = SEQ-NM;  Kn = NFULL; ksel = TOPS; vjoff = 0;
                   Kb = kfull + (size_t)bh * NFULL * HD; }
  const int b = bh / NH, h = bh % NH;
  const int q0 = qt * 32;
  const int nq = min(32, nqtot - q0);
  const ushort* qb  = qallb + (size_t)bh * SEQ * HD;
  const ushort* vTb = vT + (size_t)bh * HD * NFT + vjoff;

  bf16x8 afr[2][2];
  #pragma unroll
  for (int qf = 0; qf < 2; qf++)
    #pragma unroll
    for (int ds = 0; ds < 2; ds++){
      int qg = qbase + q0 + qf*16 + l16;
      if (qg > SEQ-1) qg = SEQ-1;
      afr[qf][ds] = *(const bf16x8*)(qb + (size_t)qg*HD + ds*32 + quad*8);
    }

  // ---------- pass 1: hi-byte histogram ----------
  for (int i2 = tid; i2 < 10272; i2 += 256) ubuf[i2] = 0;
  __syncthreads();
  for (int j0 = wave*32; j0 < Kn; j0 += 128){
    f32x4 cg[2][2];
    score_tile(afr, Kb, Kn, j0, l16, quad, cg);
    #pragma unroll
    for (int qf = 0; qf < 2; qf++)
      #pragma unroll
      for (int g = 0; g < 2; g++){
        int jj = j0 + g*16 + l16;
        if (jj < Kn){
          #pragma unroll
          for (int r = 0; r < 4; r++){
            int row = qf*16 + quad*4 + r;
            uint key = qkey(cg[qf][g][r]);
            atomicAdd(&ubuf[row*257 + (key>>8)], 1u);
          }
        }
      }
  }
  __syncthreads();
  if (tid < 32){
    uint need = (uint)ksel, cum = 0; int bsel = 0;
    for (int bb = 255; bb >= 0; bb--){
      uint hc = ubuf[tid*257 + bb];
      if (cum + hc >= need){ bsel = bb; need -= cum; break; }
      cum += hc;
    }
    hi8[tid] = (uint)bsel; needs[tid] = need;
  }
  __syncthreads();
  for (int i2 = tid; i2 < 10272; i2 += 256) ubuf[i2] = 0;
  if (tid < 32) cnts[tid] = 0;
  __syncthreads();

  // ---------- pass 2: lo-byte histogram of boundary bucket + tie list ----------
  for (int j0 = wave*32; j0 < Kn; j0 += 128){
    f32x4 cg[2][2];
    score_tile(afr, Kb, Kn, j0, l16, quad, cg);
    #pragma unroll
    for (int qf = 0; qf < 2; qf++)
      #pragma unroll
      for (int g = 0; g < 2; g++){
        int jj = j0 + g*16 + l16;
        if (jj < Kn){
          #pragma unroll
          for (int r = 0; r < 4; r++){
            int row = qf*16 + quad*4 + r;
            uint key = qkey(cg[qf][g][r]);
            if ((key>>8) == hi8[row]){
              atomicAdd(&ubuf[row*257 + (key&255u)], 1u);
              uint pos = atomicAdd(&cnts[row], 1u);
              if (pos < 64u) lst[row*64 + pos] = ((key&255u)<<16) | (uint)jj;
            }
          }
        }
      }
  }
  __syncthreads();
  if (tid < 32){
    uint need = needs[tid], cum = 0; int bsel = 0;
    for (int bb = 255; bb >= 0; bb--){
      uint hc = ubuf[tid*257 + bb];
      if (cum + hc >= need){ bsel = bb; need -= cum; break; }
      cum += hc;
    }
    tks[tid] = (hi8[tid]<<8) | (uint)bsel;
    uint n = cnts[tid];
    int jc;
    if (n > 64u) jc = Kn;               // overflow fallback: take all ties
    else {
      jc = -1;
      for (uint t = 0; t < need; t++){
        int mn = 0x7fffffff;
        for (uint i2 = 0; i2 < n; i2++){
          uint e = lst[tid*64 + i2];
          if ((e>>16) == (uint)bsel){
            int j = (int)(e & 0xFFFFu);
            if (j > jc && j < mn) mn = j;
          }
        }
        if (mn == 0x7fffffff) break;
        jc = mn;
      }
    }
    jcuts[tid] = jc;
  }
  __syncthreads();

  // ---------- pass 3: P + AV MFMA + Z ----------
  f32x4 oacc[2][4] = {};
  float zacc[2][4] = {};
  uint tkq[2][4]; int jcq[2][4]; float tvq[2][4];
  #pragma unroll
  for (int qf = 0; qf < 2; qf++)
    #pragma unroll
    for (int r = 0; r < 4; r++){
      int row = qf*16 + quad*4 + r;
      tkq[qf][r] = tks[row]; jcq[qf][r] = jcuts[row];
      tvq[qf][r] = (float)(short)(ushort)(tks[row] ^ 0x8000u) * (1.f/1024.f);
    }

  for (int j0 = wave*32; j0 < Kn; j0 += 128){
    f32x4 cg[2][2];
    score_tile(afr, Kb, Kn, j0, l16, quad, cg);
    #pragma unroll
    for (int qf = 0; qf < 2; qf++)
      #pragma unroll
      for (int g = 0; g < 2; g++){
        int jj = j0 + g*16 + l16;
        ushort4 pk;
        ushort* pku = (ushort*)&pk;
        #pragma unroll
        for (int r = 0; r < 4; r++){
          float e = 0.f;
          if (jj < Kn){
            float s = cg[qf][g][r];
            uint key = qkey(s);
            if (key > tkq[qf][r] || (key == tkq[qf][r] && jj <= jcq[qf][r])){
              e = __expf(s - tvq[qf][r]);
              zacc[qf][r] += e;
            }
          }
          pku[r] = f2bf(e);
        }
        *(ushort4*)(&Pt[wave][g*16 + l16][qf*16 + quad*4]) = pk;
      }
    bf16x8 pa[2];
    #pragma unroll
    for (int qf = 0; qf < 2; qf++){
      union { bf16x8 v; ushort u[8]; } pu;
      #pragma unroll
      for (int e = 0; e < 8; e++) pu.u[e] = Pt[wave][quad*8 + e][qf*16 + l16];
      pa[qf] = pu.v;
    }
    #pragma unroll
    for (int df = 0; df < 4; df++){
      bf16x8 bv = *(const bf16x8*)(vTb + (size_t)(df*16 + l16)*NFT + j0 + quad*8);
      oacc[0][df] = __builtin_amdgcn_mfma_f32_16x16x32_bf16(pa[0], bv, oacc[0][df], 0,0,0);
      oacc[1][df] = __builtin_amdgcn_mfma_f32_16x16x32_bf16(pa[1], bv, oacc[1][df], 0,0,0);
    }
  }

  // Z: reduce across the 16 j-lanes, then across waves
  #pragma unroll
  for (int qf = 0; qf < 2; qf++)
    #pragma unroll
    for (int r = 0; r < 4; r++){
      float v = zacc[qf][r];
      #pragma unroll
      for (int mk = 1; mk < 16; mk <<= 1) v += __shfl_xor(v, mk);
      if (l16 == 0) zpart[qf*16 + quad*4 + r][wave] = v;
    }
  __syncthreads();

  // O: sequential cross-wave reduction into redf (reuses ubuf)
  for (int w = 0; w < 4; w++){
    if (wave == w){
      #pragma unroll
      for (int qf = 0; qf < 2; qf++)
        #pragma unroll
        for (int df = 0; df < 4; df++)
          #pragma unroll
          for (int r = 0; r < 4; r++){
            int idx = (qf*16 + quad*4 + r)*64 + df*16 + l16;
            if (w == 0) redf[idx]  = oacc[qf][df][r];
            else        redf[idx] += oacc[qf][df][r];
          }
    }
    __syncthreads();
  }

  // store
  {
    int row = tid >> 3, d0 = (tid & 7) * 8;
    if (row < nq){
      float Z = zpart[row][0] + zpart[row][1] + zpart[row][2] + zpart[row][3];
      float zinv = Z > 0.f ? 1.f/Z : 0.f;
      uint4 ov; ushort* op = (ushort*)&ov;
      #pragma unroll
      for (int e = 0; e < 8; e++) op[e] = f2bf(redf[row*64 + d0 + e] * zinv);
      int qg = qbase + q0 + row;
      *(uint4*)(xcat + ((size_t)b*SEQ + qg)*CDIM + h*HD + d0) = ov;
    }
  }
}

// ======================= launch =======================
extern "C" void kernel_launch(void* const* d_in, const int* in_sizes, int n_in,
                              void* d_out, int out_size, void* d_ws, size_t ws_size,
                              hipStream_t stream)
{
  const void* x        = d_in[0];
  const void* id_total = d_in[1];
  const void* mem_k    = d_in[2];
  const void* mem_v    = d_in[3];
  const void* w_qkv    = d_in[4];
  const void* w_proj   = d_in[5];
  const void* b_proj   = d_in[6];
  const void* w_idkv   = d_in[7];
  const void* b_idkv   = d_in[8];

  char* p = (char*)d_ws;
  auto carve = [&](size_t bytes)->char*{
    char* q = p; p += (bytes + 255) & ~(size_t)255; return q;
  };
  int*    modep  = (int*)   carve(256);
  ushort* xb     = (ushort*)carve(2ull*BATCH*SEQ*CDIM);
  ushort* idb    = (ushort*)carve(2ull*BATCH*NM*CDIM);
  ushort* wqkvb  = (ushort*)carve(2ull*3*CDIM*CDIM);
  ushort* wprojb = (ushort*)carve(2ull*CDIM*CDIM);
  ushort* widkvb = (ushort*)carve(2ull*IDC*CDIM);
  float*  bprojf = (float*) carve(4ull*CDIM);
  float*  bidkvf = (float*) carve(4ull*IDC);
  float*  idkvf  = (float*) carve(4ull*BATCH*NM*IDC);
  ushort* qallb  = (ushort*)carve(2ull*BATCH*NH*SEQ*HD);
  ushort* kfull  = (ushort*)carve(2ull*BATCH*NH*NFULL*HD);
  ushort* vT     = (ushort*)carve(2ull*BATCH*NH*HD*NFT);
  ushort* kmod   = (ushort*)carve(2ull*BATCH*NH*NM*HD);
  ushort* xcat   = (ushort*)carve(2ull*BATCH*SEQ*CDIM);

  dim3 blk(256,1,1);

  hipLaunchKernelGGL(detect_mode, dim3(1), blk, 0, stream, (const uint*)w_qkv, modep);

  auto conv = [&](const void* src, ushort* dst, int n){
    hipLaunchKernelGGL(conv_in, dim3((n+255)/256), blk, 0, stream, src, dst, n, modep);
  };
  conv(x,        xb,     BATCH*SEQ*CDIM);
  conv(id_total, idb,    BATCH*NM*CDIM);
  conv(w_qkv,    wqkvb,  3*CDIM*CDIM);
  conv(w_proj,   wprojb, CDIM*CDIM);
  conv(w_idkv,   widkvb, IDC*CDIM);
  hipLaunchKernelGGL(conv_bias, dim3((CDIM+255)/256), blk, 0, stream, b_proj, bprojf, CDIM, modep);
  hipLaunchKernelGGL(conv_bias, dim3((IDC+255)/256),  blk, 0, stream, b_idkv, bidkvf, IDC, modep);
  {
    constexpr int total = BATCH*NH*NMEM*HD;
    hipLaunchKernelGGL(conv_mem, dim3((total+255)/256), blk, 0, stream,
                       mem_k, mem_v, kfull, vT, modep);
  }
  {
    int M = BATCH*NM, Nc = IDC;
    dim3 grid((M+127)/128, (Nc+127)/128, 1);
    hipLaunchKernelGGL(gemm_idkv, grid, blk, 0, stream, idb, widkvb, bidkvf, idkvf);
  }
  {
    int M = BATCH*SEQ, Nc = 3*CDIM;
    dim3 grid((M+127)/128, (Nc+127)/128, 1);
    hipLaunchKernelGGL(gemm_qkv, grid, blk, 0, stream,
                       xb, wqkvb, idkvf, qallb, kfull, vT, kmod, d_out, modep);
  }
  { // merged template+search attention, XCD-aware block mapping
    hipLaunchKernelGGL(attn_topk4, dim3(8 * NBH/8 * ITEMS_PER_BH), blk, 0, stream,
                       qallb, kmod, kfull, vT, xcat);
  }
  {
    int M = BATCH*SEQ, Nc = CDIM;
    dim3 grid((M+127)/128, (Nc+127)/128, 1);
    hipLaunchKernelGGL(gemm_proj, grid, blk, 0, stream, xcat, wprojb, bprojf, d_out, modep);
  }
}